// Round 4
// baseline (116.040 us; speedup 1.0000x reference)
//
#include <hip/hip_runtime.h>
#include <math.h>

#define NPTS  4096
#define BATCH 16
#define NTILE 128              // 4096 / 32 column tiles
#define BLKM  512              // 8 waves per min-kernel block

typedef __attribute__((ext_vector_type(8)))  short bf16x8;
typedef __attribute__((ext_vector_type(16))) float f32x16;

static __device__ __forceinline__ unsigned short f2bf(float x) {
    unsigned u = __float_as_uint(x);
    unsigned r = 0x7FFFu + ((u >> 16) & 1u);     // round-to-nearest-even
    return (unsigned short)((u + r) >> 16);
}
static __device__ __forceinline__ float bf2f(unsigned short h) {
    return __uint_as_float(((unsigned)h) << 16);
}
static __device__ __forceinline__ float min3f(float a, float b, float c) {
    return fminf(fminf(a, b), c);
}

// ---------------------------------------------------------------------------
// K-slot map (one mfma_f32_32x32x16_bf16 computes full d[n][m] for a 32x32 tile):
//   k0-2 : A=-2*ph_{x,y,z}, B=th_{x,y,z}     k3-5 : A=-2*pl, B=th
//   k6-8 : A=-2*ph,         B=tl             k9,10: A=pph,ppl  B=1
//   k11,12: A=1, B=tth,ttl                   k13-15: 0
// => D = pp[n] + tt[m] - 2*(ph·th + pl·th + ph·tl)  ~= |p-t|^2
// Lane layout (32x32x16): rows/cols = lane&31, k-group = (lane>>5)*8 + elem.
// The final scalar is invariant to D-transpose and to any A/B-consistent
// k-permutation, so residual layout uncertainty cannot corrupt the result.
// ---------------------------------------------------------------------------

// Precompute B-fragments (target side) once: [b][tile][lane] -> 8 bf16 (16 B)
__global__ __launch_bounds__(256) void prep_bfrag(
    const float* __restrict__ target, bf16x8* __restrict__ bfr)
{
    int id = blockIdx.x * 256 + threadIdx.x;          // 65536 threads, 2 iters
    #pragma unroll
    for (int it = 0; it < 2; ++it, id += 65536) {
        const int l    = id & 63;
        const int tile = (id >> 6) & (NTILE - 1);
        const int b    = id >> 13;
        const int col  = tile * 32 + (l & 31);
        const float* tp = target + ((size_t)b * NPTS + col) * 3;
        float x = tp[0], y = tp[1], z = tp[2];
        unsigned short hx = f2bf(x), hy = f2bf(y), hz = f2bf(z);
        unsigned short lx = f2bf(x - bf2f(hx));
        unsigned short ly = f2bf(y - bf2f(hy));
        unsigned short lz = f2bf(z - bf2f(hz));
        float tt = fmaf(z, z, fmaf(y, y, x * x));
        unsigned short th = f2bf(tt);
        unsigned short tl = f2bf(tt - bf2f(th));
        const short one = (short)0x3F80;
        bf16x8 v;
        if (l < 32)
            v = (bf16x8){(short)hx, (short)hy, (short)hz,
                         (short)hx, (short)hy, (short)hz,
                         (short)lx, (short)ly};
        else
            v = (bf16x8){(short)lz, one, one, (short)th, (short)tl, 0, 0, 0};
        bfr[id] = v;
    }
}

// Each block: batch b, row panel of 256 rows (8 waves x 32 rows).
// Wave sweeps all 128 col tiles: 1 mfma + ~26 VALU epilogue per tile.
__global__ __launch_bounds__(BLKM) void chamfer_mfma(
    const float* __restrict__ pred, const bf16x8* __restrict__ bfr,
    unsigned* __restrict__ gcolmin, float* __restrict__ rowsum_ws)
{
    __shared__ unsigned colmin[NPTS];          // 16 KB, per-block partial over 256 rows

    const int panel = blockIdx.x;              // 0..15
    const int b     = blockIdx.y;              // 0..15
    const int t     = threadIdx.x;
    const int w     = t >> 6;                  // wave 0..7
    const int l     = t & 63;

    for (int i = t; i < NPTS; i += BLKM) colmin[i] = 0x7F800000u;  // +inf bits

    // ---- A fragment: this wave's 32 rows ----
    const int r = l & 31;
    const int n = panel * 256 + w * 32 + r;
    const float* pp_ = pred + ((size_t)b * NPTS + n) * 3;
    {
    }
    float x = pp_[0], y = pp_[1], z = pp_[2];
    unsigned short hx = f2bf(x), hy = f2bf(y), hz = f2bf(z);
    unsigned short lx = f2bf(x - bf2f(hx));
    unsigned short ly = f2bf(y - bf2f(hy));
    unsigned short lz = f2bf(z - bf2f(hz));
    // -2*hi / -2*lo are exact bf16 rescalings
    unsigned short n2hx = f2bf(-2.0f * bf2f(hx));
    unsigned short n2hy = f2bf(-2.0f * bf2f(hy));
    unsigned short n2hz = f2bf(-2.0f * bf2f(hz));
    unsigned short n2lx = f2bf(-2.0f * bf2f(lx));
    unsigned short n2ly = f2bf(-2.0f * bf2f(ly));
    unsigned short n2lz = f2bf(-2.0f * bf2f(lz));
    float pp = fmaf(z, z, fmaf(y, y, x * x));
    unsigned short pph = f2bf(pp);
    unsigned short ppl = f2bf(pp - bf2f(pph));
    const short one = (short)0x3F80;
    bf16x8 afrag;
    if (l < 32)
        afrag = (bf16x8){(short)n2hx, (short)n2hy, (short)n2hz,
                         (short)n2lx, (short)n2ly, (short)n2lz,
                         (short)n2hx, (short)n2hy};
    else
        afrag = (bf16x8){(short)n2hz, (short)pph, (short)ppl, one, one, 0, 0, 0};

    __syncthreads();                           // colmin init visible

    f32x16 rmin;
    #pragma unroll
    for (int i = 0; i < 16; ++i) rmin[i] = INFINITY;

    const bf16x8* bbase = bfr + (size_t)b * NTILE * 64;

    for (int tile = 0; tile < NTILE; ++tile) {
        bf16x8 bft = bbase[tile * 64 + l];
        f32x16 acc;
        #pragma unroll
        for (int i = 0; i < 16; ++i) acc[i] = 0.0f;
        acc = __builtin_amdgcn_mfma_f32_32x32x16_bf16(afrag, bft, acc, 0, 0, 0);

        // rowmin: 1 v_min per element into this lane's 16 row slots
        #pragma unroll
        for (int i = 0; i < 16; ++i) rmin[i] = fminf(rmin[i], acc[i]);

        // colmin: lane's 16 elements share one col -> min3 tree -> LDS atomic
        float t0 = min3f(acc[0],  acc[1],  acc[2]);
        float t1 = min3f(acc[3],  acc[4],  acc[5]);
        float t2 = min3f(acc[6],  acc[7],  acc[8]);
        float t3 = min3f(acc[9],  acc[10], acc[11]);
        float t4 = min3f(acc[12], acc[13], acc[14]);
        float m  = fminf(min3f(t0, t1, t2), min3f(t3, t4, acc[15]));
        unsigned mu = __float_as_uint(fmaxf(m, 0.0f));   // clamp => uint order ok
        atomicMin(&colmin[tile * 32 + r], mu);
    }

    // ---- rowmin finalize: min across the 32 lanes of each half, then sum ----
    float rs = 0.0f;
    #pragma unroll
    for (int i = 0; i < 16; ++i) {
        float v = rmin[i];
        v = fminf(v, __shfl_xor(v, 1, 64));
        v = fminf(v, __shfl_xor(v, 2, 64));
        v = fminf(v, __shfl_xor(v, 4, 64));
        v = fminf(v, __shfl_xor(v, 8, 64));
        v = fminf(v, __shfl_xor(v, 16, 64));
        rs += fmaxf(v, 0.0f);
    }
    rs += __shfl_xor(rs, 32, 64);              // combine the two lane-halves
    if (l == 0) rowsum_ws[((size_t)b * 16 + panel) * 8 + w] = rs;

    __syncthreads();                           // all tiles flushed to colmin
    for (int i = t; i < NPTS; i += BLKM)
        atomicMin(&gcolmin[(size_t)b * NPTS + i], colmin[i]);
}

// Final: sum clamped colmins (already clamped) + rowsums, scale, accumulate.
__global__ __launch_bounds__(256) void chamfer_sum(
    const unsigned* __restrict__ gcolmin, const float* __restrict__ rowsum_ws,
    float* __restrict__ out)
{
    __shared__ float wsum[4];
    const int gid = blockIdx.x * 256 + threadIdx.x;   // 32 blocks -> 8192 threads

    float s = 0.0f;
    for (int i = gid; i < BATCH * NPTS; i += 8192)
        s += __uint_as_float(gcolmin[i]);
    for (int i = gid; i < BATCH * 16 * 8; i += 8192)
        s += rowsum_ws[i];

    #pragma unroll
    for (int off = 32; off > 0; off >>= 1)
        s += __shfl_down(s, off, 64);

    const int wid  = threadIdx.x >> 6;
    const int lane = threadIdx.x & 63;
    if (lane == 0) wsum[wid] = s;
    __syncthreads();

    if (threadIdx.x == 0) {
        float acc = wsum[0] + wsum[1] + wsum[2] + wsum[3];
        atomicAdd(out, acc * (1.0f / ((float)BATCH * (float)NPTS)));
    }
}

extern "C" void kernel_launch(void* const* d_in, const int* in_sizes, int n_in,
                              void* d_out, int out_size, void* d_ws, size_t ws_size,
                              hipStream_t stream) {
    const float* pred   = (const float*)d_in[0];
    const float* target = (const float*)d_in[1];
    float* out = (float*)d_out;

    char* ws = (char*)d_ws;
    bf16x8*   bfr     = (bf16x8*)ws;                                   // 2 MB
    unsigned* gcolmin = (unsigned*)(ws + (2u << 20));                  // 256 KB
    float*    rowsum  = (float*)(ws + (2u << 20) + (256u << 10));      // 8 KB

    hipMemsetAsync(gcolmin, 0x7F, (size_t)BATCH * NPTS * 4, stream);   // sentinel
    hipMemsetAsync(out, 0, sizeof(float), stream);

    prep_bfrag<<<dim3(256), 256, 0, stream>>>(target, bfr);
    chamfer_mfma<<<dim3(16, 16), BLKM, 0, stream>>>(pred, bfr, gcolmin, rowsum);
    chamfer_sum<<<dim3(32), 256, 0, stream>>>(gcolmin, rowsum, out);
}

// Round 5
// 82.711 us; speedup vs baseline: 1.4030x; 1.4030x over previous
//
#include <hip/hip_runtime.h>
#include <math.h>

#define NPTS   4096
#define BATCH  16
#define BLK    512
#define CS     4                        // column splits
#define COLS_PER_BLK (NPTS / CS)        // 1024
#define TPB    (COLS_PER_BLK / 32)      // 32 col tiles per block
#define PANELS 16                       // row panels of 256 (8 waves x 32)

typedef __attribute__((ext_vector_type(8)))  short bf16x8;
typedef __attribute__((ext_vector_type(16))) float f32x16;

static __device__ __forceinline__ unsigned short f2bf(float x) {
    unsigned u = __float_as_uint(x);
    unsigned r = 0x7FFFu + ((u >> 16) & 1u);     // RNE
    return (unsigned short)((u + r) >> 16);
}
static __device__ __forceinline__ float bf2f(unsigned short h) {
    return __uint_as_float(((unsigned)h) << 16);
}
static __device__ __forceinline__ float min3f(float a, float b, float c) {
    return fminf(fminf(a, b), c);
}

// ---------------------------------------------------------------------------
// One mfma_f32_32x32x16_bf16 per 32x32 tile gives the full distance matrix:
//   k0-2: A=-2ph,B=th   k3-5: A=-2pl,B=th   k6-8: A=-2ph,B=tl
//   k9,10: A=pph,ppl B=1     k11,12: A=1 B=tth,ttl     k13-15: 0
// => D = pp + tt - 2(ph·th + pl·th + ph·tl)  (validated round 4: absmax 0.0)
// rowmin -> pred->target direction; colmin -> target->pred. Both share D.
// ws: [0,256KB) colmin uint bits [b][4096]; [256KB,512KB) rowmin [b][4096];
// both sentinel 0x7F7F7F7F, values clamped >=0 so uint order == float order.
// ---------------------------------------------------------------------------

__global__ __launch_bounds__(BLK) void chamfer_mfma(
    const float* __restrict__ pred, const float* __restrict__ target,
    unsigned* __restrict__ gcolmin, unsigned* __restrict__ growmin)
{
    __shared__ __align__(16) bf16x8 sB[TPB * 64];   // 32 KB B-fragments
    __shared__ unsigned colmin[COLS_PER_BLK];       // 4 KB

    const int bx    = blockIdx.x;
    const int cs    = bx & (CS - 1);
    const int panel = bx >> 2;
    const int b     = blockIdx.y;
    const int t     = threadIdx.x;
    const int w     = t >> 6;
    const int l     = t & 63;
    const short one = (short)0x3F80;

    for (int i = t; i < COLS_PER_BLK; i += BLK) colmin[i] = 0x7F800000u;

    // ---- stage B fragments for this block's 1024 columns ----
    const int colbase = cs * COLS_PER_BLK;
    for (int e = t; e < TPB * 64; e += BLK) {
        const int el   = e & 63;
        const int tile = e >> 6;
        const int col  = colbase + tile * 32 + (el & 31);
        const float* tp = target + ((size_t)b * NPTS + col) * 3;
        float x = tp[0], y = tp[1], z = tp[2];
        unsigned short hx = f2bf(x), hy = f2bf(y), hz = f2bf(z);
        unsigned short lx = f2bf(x - bf2f(hx));
        unsigned short ly = f2bf(y - bf2f(hy));
        unsigned short lz = f2bf(z - bf2f(hz));
        float tt = fmaf(z, z, fmaf(y, y, x * x));
        unsigned short th = f2bf(tt);
        unsigned short tl = f2bf(tt - bf2f(th));
        bf16x8 v;
        if (el < 32)
            v = (bf16x8){(short)hx, (short)hy, (short)hz,
                         (short)hx, (short)hy, (short)hz,
                         (short)lx, (short)ly};
        else
            v = (bf16x8){(short)lz, one, one, (short)th, (short)tl, 0, 0, 0};
        sB[e] = v;
    }

    // ---- A fragment: this wave's 32 rows ----
    const int r   = l & 31;
    const int row = panel * 256 + w * 32 + r;
    const float* pp_ = pred + ((size_t)b * NPTS + row) * 3;
    float x = pp_[0], y = pp_[1], z = pp_[2];
    unsigned short hx = f2bf(x), hy = f2bf(y), hz = f2bf(z);
    unsigned short lx = f2bf(x - bf2f(hx));
    unsigned short ly = f2bf(y - bf2f(hy));
    unsigned short lz = f2bf(z - bf2f(hz));
    unsigned short n2hx = f2bf(-2.0f * bf2f(hx));
    unsigned short n2hy = f2bf(-2.0f * bf2f(hy));
    unsigned short n2hz = f2bf(-2.0f * bf2f(hz));
    unsigned short n2lx = f2bf(-2.0f * bf2f(lx));
    unsigned short n2ly = f2bf(-2.0f * bf2f(ly));
    unsigned short n2lz = f2bf(-2.0f * bf2f(lz));
    float pp = fmaf(z, z, fmaf(y, y, x * x));
    unsigned short pph = f2bf(pp);
    unsigned short ppl = f2bf(pp - bf2f(pph));
    bf16x8 afrag;
    if (l < 32)
        afrag = (bf16x8){(short)n2hx, (short)n2hy, (short)n2hz,
                         (short)n2lx, (short)n2ly, (short)n2lz,
                         (short)n2hx, (short)n2hy};
    else
        afrag = (bf16x8){(short)n2hz, (short)pph, (short)ppl, one, one, 0, 0, 0};

    __syncthreads();

    f32x16 rmin;
    #pragma unroll
    for (int i = 0; i < 16; ++i) rmin[i] = INFINITY;
    f32x16 zacc;
    #pragma unroll
    for (int i = 0; i < 16; ++i) zacc[i] = 0.0f;

    #pragma unroll 2
    for (int tile = 0; tile < TPB; ++tile) {
        bf16x8 bft = sB[tile * 64 + l];
        f32x16 acc = __builtin_amdgcn_mfma_f32_32x32x16_bf16(afrag, bft, zacc, 0, 0, 0);

        #pragma unroll
        for (int i = 0; i < 16; ++i) rmin[i] = fminf(rmin[i], acc[i]);

        float t0 = min3f(acc[0],  acc[1],  acc[2]);
        float t1 = min3f(acc[3],  acc[4],  acc[5]);
        float t2 = min3f(acc[6],  acc[7],  acc[8]);
        float t3 = min3f(acc[9],  acc[10], acc[11]);
        float t4 = min3f(acc[12], acc[13], acc[14]);
        float m  = fminf(min3f(t0, t1, t2), min3f(t3, t4, acc[15]));
        atomicMin(&colmin[tile * 32 + r], __float_as_uint(fmaxf(m, 0.0f)));
    }

    // ---- rowmin: reduce over the 32 cols in each lane-half ----
    #pragma unroll
    for (int i = 0; i < 16; ++i) {
        float v = rmin[i];
        v = fminf(v, __shfl_xor(v, 1, 64));
        v = fminf(v, __shfl_xor(v, 2, 64));
        v = fminf(v, __shfl_xor(v, 4, 64));
        v = fminf(v, __shfl_xor(v, 8, 64));
        v = fminf(v, __shfl_xor(v, 16, 64));
        rmin[i] = v;
    }
    if ((l & 31) == 0) {
        const int h = l >> 5;
        unsigned* rb = growmin + (size_t)b * NPTS + panel * 256 + w * 32;
        #pragma unroll
        for (int i = 0; i < 16; ++i) {
            const int rloc = (i & 3) + 8 * (i >> 2) + 4 * h;
            atomicMin(&rb[rloc], __float_as_uint(fmaxf(rmin[i], 0.0f)));
        }
    }

    __syncthreads();
    unsigned* cb = gcolmin + (size_t)b * NPTS + colbase;
    for (int i = t; i < COLS_PER_BLK; i += BLK)
        atomicMin(&cb[i], colmin[i]);
}

// Sum both min arrays (131072 uints, all clamped >= 0), scale, atomicAdd out.
__global__ __launch_bounds__(256) void chamfer_sum(
    const uint4* __restrict__ mins, float* __restrict__ out)
{
    __shared__ float wsum[4];
    const int gid = blockIdx.x * 256 + threadIdx.x;   // 32 blocks = 8192 threads

    float s = 0.0f;
    for (int i = gid; i < (2 * BATCH * NPTS) / 4; i += 8192) {
        uint4 v = mins[i];
        s += __uint_as_float(v.x) + __uint_as_float(v.y)
           + __uint_as_float(v.z) + __uint_as_float(v.w);
    }

    #pragma unroll
    for (int off = 32; off > 0; off >>= 1)
        s += __shfl_down(s, off, 64);

    if ((threadIdx.x & 63) == 0) wsum[threadIdx.x >> 6] = s;
    __syncthreads();

    if (threadIdx.x == 0) {
        float acc = wsum[0] + wsum[1] + wsum[2] + wsum[3];
        atomicAdd(out, acc * (1.0f / ((float)BATCH * (float)NPTS)));
    }
}

extern "C" void kernel_launch(void* const* d_in, const int* in_sizes, int n_in,
                              void* d_out, int out_size, void* d_ws, size_t ws_size,
                              hipStream_t stream) {
    const float* pred   = (const float*)d_in[0];
    const float* target = (const float*)d_in[1];
    float* out = (float*)d_out;

    unsigned* gcolmin = (unsigned*)d_ws;                       // 256 KB
    unsigned* growmin = gcolmin + (size_t)BATCH * NPTS;        // 256 KB

    hipMemsetAsync(d_ws, 0x7F, (size_t)2 * BATCH * NPTS * 4, stream);
    hipMemsetAsync(out, 0, sizeof(float), stream);

    chamfer_mfma<<<dim3(CS * PANELS, BATCH), BLK, 0, stream>>>(
        pred, target, gcolmin, growmin);
    chamfer_sum<<<dim3(32), 256, 0, stream>>>((const uint4*)d_ws, out);
}